// Round 12
// baseline (452.342 us; speedup 1.0000x reference)
//
#include <hip/hip_runtime.h>
#include <hip/hip_bf16.h>

#define HH 4
#define NR 20000
#define DIN 257
#define DS 256
#define MF 64
#define KP 288   // padded K for bf16 staging; k=257 is the bias-1 slot
#define VP 264   // v row stride in bf16 elems (264*2=528 B, 16B-aligned rows)
#define LTP 272  // lastT padded d-rows
#define ZST 276  // fuse3 LDS z-tile row stride
#define LKC 25   // last3 split-K: 25 grid x 25 chunks x 32 rows = 20000

typedef __bf16 bf16;
typedef bf16 bf16x8 __attribute__((ext_vector_type(8)));
typedef bf16 bf16x4 __attribute__((ext_vector_type(4)));
typedef bf16 bf16x2 __attribute__((ext_vector_type(2)));
typedef float f32x4 __attribute__((ext_vector_type(4)));
typedef unsigned int u32x4 __attribute__((ext_vector_type(4)));

// ---------------------------------------------------------------------------
// conversions
// ---------------------------------------------------------------------------
__global__ void cvt_x_kernel(const float* __restrict__ xA, const float* __restrict__ xB,
                             bf16* __restrict__ xbA, bf16* __restrict__ xbB) {
  const int n = blockIdx.x, k = threadIdx.x;  // 288 threads, y = side
  const float* x = blockIdx.y ? xB : xA;
  bf16* xb = blockIdx.y ? xbB : xbA;
  bf16 v = (bf16)0.f;
  if (k < DIN) v = (bf16)x[(long)n * DIN + k];
  else if (k == DIN) v = (bf16)1.f;  // bias-1 slot (WbT pads are 0 there)
  xb[(long)n * KP + k] = v;
}

__global__ void cvt_w_kernel(const float* __restrict__ Wq, const float* __restrict__ Wk,
                             const float* __restrict__ Wv, bf16* __restrict__ WbTq,
                             bf16* __restrict__ WbTk, bf16* __restrict__ WbTv) {
  const int which = blockIdx.y;
  const int h = blockIdx.x >> 8, n = blockIdx.x & 255, k = threadIdx.x;
  const float* W = which == 0 ? Wq : (which == 1 ? Wk : Wv);
  bf16* o = which == 0 ? WbTq : (which == 1 ? WbTk : WbTv);
  o[((long)h * 256 + n) * KP + k] =
      (k < DIN) ? (bf16)W[((long)h * DIN + k) * DS + n] : (bf16)0.f;
}

// WpT[(which*HH+h)][m][k] = sum_d W[h][k][d]*proj[d][m]; k=257 row = b.proj
__global__ void cvt_wp_kernel(const float* __restrict__ Wq, const float* __restrict__ Wk,
                              const float* __restrict__ bq, const float* __restrict__ bk,
                              const float* __restrict__ proj, bf16* __restrict__ WpT) {
  const int k = blockIdx.x, h = blockIdx.y, which = blockIdx.z, m = threadIdx.x;
  const float* W = which ? Wk : Wq;
  const float* bb = which ? bk : bq;
  float acc = 0.f;
  if (k < DIN) {
    const float* wr = W + ((long)h * DIN + k) * DS;
#pragma unroll 8
    for (int d = 0; d < DS; d++) acc = fmaf(wr[d], proj[(long)d * MF + m], acc);
  } else if (k == DIN) {
    const float* br = bb + (long)h * DS;
#pragma unroll 8
    for (int d = 0; d < DS; d++) acc = fmaf(br[d], proj[(long)d * MF + m], acc);
  }
  WpT[(((long)which * HH + h) * MF + m) * KP + k] = (bf16)acc;
}

// ---------------------------------------------------------------------------
// async global->LDS 16B helper
// ---------------------------------------------------------------------------
__device__ __forceinline__ void gl_lds16(const bf16* g, bf16* l) {
  __builtin_amdgcn_global_load_lds(
      (const __attribute__((address_space(1))) unsigned int*)g,
      (__attribute__((address_space(3))) unsigned int*)l, 16, 0, 0);
}

// ---------------------------------------------------------------------------
// proj4+feat fused: LDS-staged double-buffered projection GEMM. grid (24, 313).
// blockIdx.x = zh (z*4+h, FAST dim -> A-tile L2 reuse across the 8 XCDs).
// z: 0=value-u 1=value-i 2=q-u 3=k-u 4=q-i 5=k-i
// Block = 64 rows x 256 cols, 4 waves, acc 4x4; R7-verified 2-barrier sync.
// z>=2 blocks also compute the feat output (x @ WpT slice) and consume their
// own row-norms as fr from LDS (standalone feat kernel eliminated, R10).
// ---------------------------------------------------------------------------
__global__ __launch_bounds__(256) void proj4_kernel(
    const bf16* __restrict__ xbA, const bf16* __restrict__ xbB,
    const bf16* __restrict__ WbTq, const bf16* __restrict__ WbTk,
    const bf16* __restrict__ WbTv, const bf16* __restrict__ WpT,
    const float* __restrict__ bq, const float* __restrict__ bk,
    const float* __restrict__ bv,
    bf16* __restrict__ voA, bf16* __restrict__ voB,
    bf16* __restrict__ qpA, bf16* __restrict__ kpA,
    bf16* __restrict__ qpB, bf16* __restrict__ kpB)
{
  // 40 KB carved LDS: A dbuf [2][64*32] bf16 = 8 KB, B dbuf [2][256*32] = 32 KB.
  // rs[64][4] (smem+0) and frl[64] (smem+2048) overlay the A buffers after
  // the K-loop (barrier-protected).
  __shared__ __align__(16) char smem[40960];
  bf16* Ab = (bf16*)smem;              // 2 * 2048 elems
  bf16* Bb = (bf16*)(smem + 8192);     // 2 * 8192 elems
  float (*rs)[4] = (float(*)[4])smem;
  float* frl = (float*)(smem + 2048);

  const int t = threadIdx.x;
  const int zh = blockIdx.x;
  const int h = zh & 3;
  const int z = zh >> 2;
  const int n0 = blockIdx.y * 64;
  const bf16* xb = (z == 1 || z >= 4) ? xbB : xbA;
  const bf16* WbT = (z < 2) ? WbTv : ((z == 2 || z == 4) ? WbTq : WbTk);
  const float* bsel = (z < 2) ? bv : ((z == 2 || z == 4) ? bq : bk);
  const int w = t >> 6, lane = t & 63;
  const int m16 = lane & 15, q = lane >> 4;
  const bf16* wbh = WbT + (long)h * 256 * KP;

  // staging geometry: wave w stages rows w*16..w*16+15 of each 64-row panel;
  // lane l covers row w*16+(l>>2), col (l&3)*8 (16B per lane, linear in LDS).
  const int rsub = w * 16 + (lane >> 2);
  const int cb = (lane & 3) * 8;
  const bf16* gA = xb + (long)min(n0 + rsub, NR - 1) * KP + cb;
  const bf16* gB = wbh + (long)rsub * KP + cb;

  // feat B-operand (z>=2): wave w owns WpT cols w*16..w*16+15.
  const int which = (z == 2 || z == 4) ? 0 : 1;
  const bf16* gWp = WpT + (((long)which * HH + h) * MF + (w * 16 + m16)) * KP + q * 8;

#define STAGE(buf, c)                                                        \
  do {                                                                       \
    const int _k0 = (c) * 32;                                                \
    gl_lds16(gA + _k0, Ab + (buf) * 2048 + w * 512);                         \
    _Pragma("unroll")                                                        \
    for (int e = 0; e < 4; e++)                                              \
      gl_lds16(gB + (long)e * 64 * KP + _k0,                                 \
               Bb + (buf) * 8192 + e * 2048 + w * 512);                      \
  } while (0)

  f32x4 acc[4][4] = {};
  f32x4 acc5[4] = {};
  STAGE(0, 0);

  for (int c = 0; c < 9; c++) {
    const int cur = c & 1;
    __syncthreads();  // drains vmcnt -> buf[cur] landed; all waves done with buf[1-cur]
    if (c < 8) STAGE(1 - cur, c + 1);

    bf16x8 af[4], bfj[4];
#pragma unroll
    for (int i = 0; i < 4; i++)
      af[i] = *(const bf16x8*)(Ab + cur * 2048 + (i * 16 + m16) * 32 + q * 8);
#pragma unroll
    for (int j = 0; j < 4; j++)
      bfj[j] = *(const bf16x8*)(Bb + cur * 8192 + (w * 64 + j * 16 + m16) * 32 + q * 8);
#pragma unroll
    for (int i = 0; i < 4; i++)
#pragma unroll
      for (int j = 0; j < 4; j++)
        acc[i][j] = __builtin_amdgcn_mfma_f32_16x16x32_bf16(af[i], bfj[j], acc[i][j], 0, 0, 0);
    if (z >= 2) {
      const bf16x8 bf5 = *(const bf16x8*)(gWp + c * 32);
#pragma unroll
      for (int i = 0; i < 4; i++)
        acc5[i] = __builtin_amdgcn_mfma_f32_16x16x32_bf16(af[i], bf5, acc5[i], 0, 0, 0);
    }
  }
#undef STAGE

  __syncthreads();  // all waves done reading Ab before rs/frl overlay it

  float bias[4];
#pragma unroll
  for (int j = 0; j < 4; j++) bias[j] = bsel[h * DS + w * 64 + j * 16 + m16];
#pragma unroll
  for (int i = 0; i < 4; i++)
#pragma unroll
    for (int r = 0; r < 4; r++) {
      float s = 0.f;
#pragma unroll
      for (int j = 0; j < 4; j++) {
        acc[i][j][r] += bias[j];
        s = fmaf(acc[i][j][r], acc[i][j][r], s);
      }
      for (int off = 1; off < 16; off <<= 1) s += __shfl_xor(s, off);
      if (m16 == 0) rs[i * 16 + q * 4 + r][w] = s;
    }
  __syncthreads();

  if (z < 2) {
    bf16* vout = z ? voB : voA;
    if (t < 64) {
      const float ss = rs[t][0] + rs[t][1] + rs[t][2] + rs[t][3];
      if (n0 + t < NR) vout[((long)h * NR + n0 + t) * VP] = (bf16)sqrtf(1.f + ss);
    }
#pragma unroll
    for (int i = 0; i < 4; i++) {
      const int row = i * 16 + q * 4;
#pragma unroll
      for (int r = 0; r < 4; r++) {
        const int rg = n0 + row + r;
        if (rg < NR) {
          bf16* vo = vout + ((long)h * NR + rg) * VP + 1 + w * 64 + m16;
          vo[0] = (bf16)acc[i][0][r]; vo[16] = (bf16)acc[i][1][r];
          vo[32] = (bf16)acc[i][2][r]; vo[48] = (bf16)acc[i][3][r];
        }
      }
    }
  } else {
    // fr into LDS (row-norm front factor), then feat output from acc5.
    if (t < 64) {
      const float ss = rs[t][0] + rs[t][1] + rs[t][2] + rs[t][3];
      frl[t] = 0.125f * __expf(-ss) + 1e-8f;
    }
    __syncthreads();
    bf16* fout = (z == 2) ? qpA : (z == 3) ? kpA : (z == 4) ? qpB : kpB;
    const float SQ2 = 1.41421356237309515f;
#pragma unroll
    for (int i = 0; i < 4; i++) {
      const int row = i * 16 + q * 4;
#pragma unroll
      for (int r = 0; r < 4; r++) {
        const int rg = n0 + row + r;
        if (rg < NR) {
          const float frv = frl[row + r];
          fout[((long)h * NR + rg) * MF + w * 16 + m16] =
              (bf16)(__expf(SQ2 * acc5[i][r]) * frv);
        }
      }
    }
  }
}

// ---------------------------------------------------------------------------
// last3: MFMA lastT[d][m] = sum_n v[n][d]*f[n][m]. grid (5, 25, 8).
// R11: 1-deep register double-buffer (T14 issue-early): chunk c+1's v/f
// global loads issue before chunk c's barrier and are consumed in the next
// write phase -- HBM latency hides under the MFMA phase + barriers.
// Sync structure unchanged (2 __syncthreads per chunk).
// ---------------------------------------------------------------------------
__global__ __launch_bounds__(256) void last3_kernel(
    const bf16* __restrict__ vA, const bf16* __restrict__ fA,
    const bf16* __restrict__ vB, const bf16* __restrict__ fB,
    float* __restrict__ part)
{
  __shared__ unsigned int Va[64 * 17];
  __shared__ unsigned int Fa[64 * 17];
  const int t = threadIdx.x;
  const int dt = blockIdx.x, kc = blockIdx.y, z = blockIdx.z;
  const int side = z >> 2, h = z & 3;
  const bf16* v = side ? vB : vA;
  const bf16* f = side ? fB : fA;
  const int d0 = dt * 64;
  const int w = t >> 6, lane = t & 63;
  const int m16 = lane & 15, q = lane >> 4;
  const int np = t >> 4, xg = (t & 15) * 4;
  f32x4 acc[4] = {};

  auto loadv = [&](int c, bf16x4& a0, bf16x4& a1) {
    const int n0c = (kc * LKC + c) * 32;
    const bf16* s0 = v + ((long)h * NR + n0c + 2 * np) * VP + d0 + xg;
    const bf16* s1 = s0 + VP;
    if (d0 + xg + 3 < DIN) {
      a0 = *(const bf16x4*)s0;
      a1 = *(const bf16x4*)s1;
    } else {
#pragma unroll
      for (int e = 0; e < 4; e++) {
        const bool ok = (d0 + xg + e < DIN);
        a0[e] = ok ? s0[e] : (bf16)0.f;
        a1[e] = ok ? s1[e] : (bf16)0.f;
      }
    }
  };
  auto loadf = [&](int c, bf16x4& g0, bf16x4& g1) {
    const int n0c = (kc * LKC + c) * 32;
    const bf16* s0 = f + ((long)h * NR + n0c + 2 * np) * MF + xg;
    g0 = *(const bf16x4*)s0;
    g1 = *(const bf16x4*)(s0 + MF);
  };

  bf16x4 va0, va1, vf0, vf1;
  loadv(0, va0, va1);
  loadf(0, vf0, vf1);

  for (int c = 0; c < LKC; c++) {
    // write phase from registers (chunk c)
#pragma unroll
    for (int e = 0; e < 4; e++) {
      bf16x2 pv; pv[0] = va0[e]; pv[1] = va1[e];
      Va[(xg + e) * 17 + np] = __builtin_bit_cast(unsigned int, pv);
      bf16x2 pf; pf[0] = vf0[e]; pf[1] = vf1[e];
      Fa[(xg + e) * 17 + np] = __builtin_bit_cast(unsigned int, pf);
    }
    // prefetch chunk c+1 (issued before the barrier, consumed next iter)
    bf16x4 na0 = va0, na1 = va1, nf0 = vf0, nf1 = vf1;
    if (c + 1 < LKC) { loadv(c + 1, na0, na1); loadf(c + 1, nf0, nf1); }
    __syncthreads();
    u32x4 bw;
#pragma unroll
    for (int c4 = 0; c4 < 4; c4++) bw[c4] = Fa[(w * 16 + m16) * 17 + q * 4 + c4];
    const bf16x8 bvv = __builtin_bit_cast(bf16x8, bw);
#pragma unroll
    for (int i = 0; i < 4; i++) {
      u32x4 aw;
#pragma unroll
      for (int c4 = 0; c4 < 4; c4++) aw[c4] = Va[(i * 16 + m16) * 17 + q * 4 + c4];
      acc[i] = __builtin_amdgcn_mfma_f32_16x16x32_bf16(
          __builtin_bit_cast(bf16x8, aw), bvv, acc[i], 0, 0, 0);
    }
    __syncthreads();
    va0 = na0; va1 = na1; vf0 = nf0; vf1 = nf1;
  }
  float* pp = part + ((long)(z * LKC + kc) * 5 + dt) * 4096;
#pragma unroll
  for (int i = 0; i < 4; i++)
#pragma unroll
    for (int r = 0; r < 4; r++)
      pp[(i * 16 + q * 4 + r) * 64 + w * 16 + m16] = acc[i][r];
}

__global__ void reduce_last4(const float* __restrict__ part,
                             bf16* __restrict__ hiU, bf16* __restrict__ loU,
                             bf16* __restrict__ hiI, bf16* __restrict__ loI) {
  const int d = blockIdx.x, zz = blockIdx.y, m = threadIdx.x;  // (272, 8) x 64
  const int side = zz >> 2, h = zz & 3;
  const int dt = d >> 6, dl = d & 63;
  float s = 0.f;
#pragma unroll 5
  for (int kc = 0; kc < LKC; kc++)
    s += part[((long)(zz * LKC + kc) * 5 + dt) * 4096 + dl * 64 + m];
  bf16* hi = side ? hiI : hiU;
  bf16* lo = side ? loI : loU;
  const bf16 hv = (bf16)s;
  hi[((long)h * LTP + d) * MF + m] = hv;
  lo[((long)h * LTP + d) * MF + m] = (bf16)(s - (float)hv);
}

// ---------------------------------------------------------------------------
// fuse3: v is BF16 (VP-stride rows); vreg converted bf16->f32 on load.
// R11: 1-deep pipeline of the jt-loop hi/lo fragment loads (load jt+1's
// L2-resident lastT frags before jt's MFMAs -- removes ~200cy exposed
// latency per jt). Sync structure unchanged.
// ---------------------------------------------------------------------------
__global__ __launch_bounds__(256) void fuse3_kernel(
    const bf16* __restrict__ qpA, const bf16* __restrict__ vA,
    const bf16* __restrict__ hiA, const bf16* __restrict__ loA,
    const bf16* __restrict__ qpB, const bf16* __restrict__ vB,
    const bf16* __restrict__ hiB, const bf16* __restrict__ loB,
    float* __restrict__ out)
{
  __shared__ __align__(16) float zs[32 * ZST];

  const int side = blockIdx.y;
  const bf16* qp = side ? qpB : qpA;
  const bf16* v = side ? vB : vA;
  const bf16* hi = side ? hiB : hiA;
  const bf16* lo = side ? loB : loA;
  float* o = out + (long)side * NR * DIN;

  const int t = threadIdx.x;
  const int n0 = blockIdx.x * 32;
  const int w = t >> 6, lane = t & 63;
  const int m16 = lane & 15, q = lane >> 4;
  const int erow = t >> 3, ecol = (t & 7) * 4;
  const bool lead = ((t & 7) == 0);
  const int ntile = (w == 0) ? 5 : 4;

  f32x4 macc[8] = {};
  float macc256 = 0.f;

  for (int h = 0; h < HH; h++) {
    const bf16* vr = v + ((long)h * NR + n0 + erow) * VP;
    f32x4 vreg[8];
#pragma unroll
    for (int it = 0; it < 8; it++) {
      const bf16x4 vb = *(const bf16x4*)(vr + it * 32 + ecol);
#pragma unroll
      for (int c = 0; c < 4; c++) vreg[it][c] = (float)vb[c];
    }
    float v256 = lead ? (float)vr[256] : 0.f;

    bf16x8 af[2][2];
#pragma unroll
    for (int i = 0; i < 2; i++)
#pragma unroll
      for (int hf = 0; hf < 2; hf++)
        af[i][hf] = *(const bf16x8*)(qp + ((long)h * NR + n0 + i * 16 + m16) * MF + hf * 32 + q * 8);

    // jt-loop with 1-deep fragment pipeline
    int d_cur = w * 16 + m16;  // jt=0 -> dt=w
    bf16x8 bh0c, bh1c, bl0c, bl1c;
    {
      const bf16* ph = hi + ((long)h * LTP + d_cur) * MF + q * 8;
      const bf16* pl = lo + ((long)h * LTP + d_cur) * MF + q * 8;
      bh0c = *(const bf16x8*)ph; bh1c = *(const bf16x8*)(ph + 32);
      bl0c = *(const bf16x8*)pl; bl1c = *(const bf16x8*)(pl + 32);
    }
    for (int jt = 0; jt < ntile; jt++) {
      bf16x8 bh0n = bh0c, bh1n = bh1c, bl0n = bl0c, bl1n = bl1c;
      int d_nxt = d_cur;
      if (jt + 1 < ntile) {
        const int dtn = (jt + 1 < 4) ? (w + (jt + 1) * 4) : 16;
        d_nxt = dtn * 16 + m16;
        const bf16* ph = hi + ((long)h * LTP + d_nxt) * MF + q * 8;
        const bf16* pl = lo + ((long)h * LTP + d_nxt) * MF + q * 8;
        bh0n = *(const bf16x8*)ph; bh1n = *(const bf16x8*)(ph + 32);
        bl0n = *(const bf16x8*)pl; bl1n = *(const bf16x8*)(pl + 32);
      }
#pragma unroll
      for (int i = 0; i < 2; i++) {
        f32x4 a = {0.f, 0.f, 0.f, 0.f};
        a = __builtin_amdgcn_mfma_f32_16x16x32_bf16(af[i][1], bl1c, a, 0, 0, 0);
        a = __builtin_amdgcn_mfma_f32_16x16x32_bf16(af[i][0], bl0c, a, 0, 0, 0);
        a = __builtin_amdgcn_mfma_f32_16x16x32_bf16(af[i][1], bh1c, a, 0, 0, 0);
        a = __builtin_amdgcn_mfma_f32_16x16x32_bf16(af[i][0], bh0c, a, 0, 0, 0);
#pragma unroll
        for (int r = 0; r < 4; r++)
          zs[(i * 16 + q * 4 + r) * ZST + d_cur] = a[r];
      }
      bh0c = bh0n; bh1c = bh1n; bl0c = bl0n; bl1c = bl1n; d_cur = d_nxt;
    }
    __syncthreads();

    f32x4 zreg[8];
    float sz2 = 0.f, svz = 0.f, z0p = 0.f, v02p = 0.f;
#pragma unroll
    for (int it = 0; it < 8; it++) {
      zreg[it] = *(const f32x4*)&zs[erow * ZST + it * 32 + ecol];
#pragma unroll
      for (int c = 0; c < 4; c++) {
        sz2 = fmaf(zreg[it][c], zreg[it][c], sz2);
        svz = fmaf(vreg[it][c], zreg[it][c], svz);
      }
    }
    float z256 = 0.f;
    if (lead) {
      z256 = zs[erow * ZST + 256];
      sz2 = fmaf(z256, z256, sz2);
      svz = fmaf(v256, z256, svz);
      z0p = zreg[0][0];
      v02p = vreg[0][0] * vreg[0][0];
    }
#pragma unroll
    for (int off = 1; off < 8; off <<= 1) {
      sz2 += __shfl_xor(sz2, off);
      svz += __shfl_xor(svz, off);
      z0p += __shfl_xor(z0p, off);
      v02p += __shfl_xor(v02p, off);
    }
    const float a2 = 2.f * v02p - 1.f;
    const float mn = sz2 - 2.f * z0p * z0p;
    const float cf = 1.f / sqrtf(fabsf(mn + 1e-7f));
    const float ab = cf * svz;
    const float b2 = cf * cf * sz2;
    const float den = 1.f + 2.f * ab + a2 * b2;
    const float inv = 0.25f / (den + 1e-7f);
    const float sx = (1.f + 2.f * ab + b2) * inv;
    const float sy = (1.f - a2) * cf * inv;
#pragma unroll
    for (int it = 0; it < 8; it++)
#pragma unroll
      for (int c = 0; c < 4; c++)
        macc[it][c] = fmaf(sx, vreg[it][c], fmaf(sy, zreg[it][c], macc[it][c]));
    if (lead) macc256 = fmaf(sx, v256, fmaf(sy, z256, macc256));
    __syncthreads();
  }

  float sm2 = 0.f, m02p = 0.f;
#pragma unroll
  for (int it = 0; it < 8; it++)
#pragma unroll
    for (int c = 0; c < 4; c++) sm2 = fmaf(macc[it][c], macc[it][c], sm2);
  if (lead) {
    sm2 = fmaf(macc256, macc256, sm2);
    m02p = macc[0][0] * macc[0][0];
  }
#pragma unroll
  for (int off = 1; off < 8; off <<= 1) {
    sm2 += __shfl_xor(sm2, off);
    m02p += __shfl_xor(m02p, off);
  }
  const float fv = 1.f / sqrtf(fabsf(sm2 - 2.f * m02p) + 1e-7f);
  float* orow = o + (long)(n0 + erow) * DIN;
#pragma unroll
  for (int it = 0; it < 8; it++)
#pragma unroll
    for (int c = 0; c < 4; c++) orow[it * 32 + ecol + c] = macc[it][c] * fv;
  if (lead) orow[256] = macc256 * fv;
}

extern "C" void kernel_launch(void* const* d_in, const int* in_sizes, int n_in,
                              void* d_out, int out_size, void* d_ws, size_t ws_size,
                              hipStream_t stream) {
  const float* u    = (const float*)d_in[0];
  const float* ii   = (const float*)d_in[1];
  const float* Wk   = (const float*)d_in[2];
  const float* bk   = (const float*)d_in[3];
  const float* Wq   = (const float*)d_in[4];
  const float* bq   = (const float*)d_in[5];
  const float* Wv   = (const float*)d_in[6];
  const float* bv   = (const float*)d_in[7];
  const float* proj = (const float*)d_in[8];
  float* out = (float*)d_out;

  const long NVB = (long)HH * NR * VP;   // v in bf16, VP-padded rows
  const long NF = (long)HH * NR * MF;
  const long NLT = (long)HH * LTP * MF;
  bf16* v_u = (bf16*)d_ws;
  bf16* v_i = v_u + NVB;
  bf16* qp_u = v_i + NVB;
  bf16* kp_u = qp_u + NF;
  bf16* qp_i = kp_u + NF;
  bf16* kp_i = qp_i + NF;
  bf16* ltHi_u = kp_i + NF;
  bf16* ltLo_u = ltHi_u + NLT;
  bf16* ltHi_i = ltLo_u + NLT;
  bf16* ltLo_i = ltHi_i + NLT;
  bf16* xb_u  = ltLo_i + NLT;
  bf16* xb_i  = xb_u + (long)NR * KP;
  bf16* WbTq  = xb_i + (long)NR * KP;
  bf16* WbTk  = WbTq + 4 * 256 * KP;
  bf16* WbTv  = WbTk + 4 * 256 * KP;
  bf16* WpT   = WbTv + 4 * 256 * KP;   // 8 * 64 * KP bf16
  float* part = (float*)xb_u;  // 16.4 MB split-K partials, alias xb (dead after proj4)

  cvt_x_kernel<<<dim3(NR, 2), KP, 0, stream>>>(u, ii, xb_u, xb_i);
  cvt_w_kernel<<<dim3(1024, 3), KP, 0, stream>>>(Wq, Wk, Wv, WbTq, WbTk, WbTv);
  cvt_wp_kernel<<<dim3(KP, HH, 2), 64, 0, stream>>>(Wq, Wk, bq, bk, proj, WpT);

  // zh fast (24 A-sharing blocks consecutive -> XCD L2 reuse), 64-row tiles.
  // feat fused into z>=2 blocks (qp/kp written here; fr internal to LDS).
  proj4_kernel<<<dim3(24, (NR + 63) / 64), 256, 0, stream>>>(
      xb_u, xb_i, WbTq, WbTk, WbTv, WpT, bq, bk, bv,
      v_u, v_i, qp_u, kp_u, qp_i, kp_i);

  // side 0 (-> lastT_u) uses (v_i, kp_i); side 1 (-> lastT_i) uses (v_u, kp_u)
  last3_kernel<<<dim3(5, LKC, 8), 256, 0, stream>>>(v_i, kp_i, v_u, kp_u, part);
  reduce_last4<<<dim3(LTP, 8), 64, 0, stream>>>(part, ltHi_u, ltLo_u, ltHi_i, ltLo_i);

  fuse3_kernel<<<dim3(NR / 32, 2), 256, 0, stream>>>(
      qp_u, v_u, ltHi_u, ltLo_u, qp_i, v_i, ltHi_i, ltLo_i, out);
}

// Round 15
// 443.652 us; speedup vs baseline: 1.0196x; 1.0196x over previous
//
#include <hip/hip_runtime.h>
#include <hip/hip_bf16.h>

#define HH 4
#define NR 20000
#define DIN 257
#define DS 256
#define MF 64
#define KP 288   // padded K for bf16 staging; k=257 is the bias-1 slot
#define VP 264   // v row stride in bf16 elems (264*2=528 B, 16B-aligned rows)
#define LTP 272  // lastT padded d-rows
#define ZST 276  // fuse3 LDS z-tile row stride
#define LKC 25   // last3 split-K: 25 grid x 25 chunks x 32 rows = 20000

typedef __bf16 bf16;
typedef bf16 bf16x8 __attribute__((ext_vector_type(8)));
typedef bf16 bf16x4 __attribute__((ext_vector_type(4)));
typedef bf16 bf16x2 __attribute__((ext_vector_type(2)));
typedef float f32x4 __attribute__((ext_vector_type(4)));
typedef unsigned int u32x4 __attribute__((ext_vector_type(4)));

// ---------------------------------------------------------------------------
// conversions
// ---------------------------------------------------------------------------
__global__ void cvt_x_kernel(const float* __restrict__ xA, const float* __restrict__ xB,
                             bf16* __restrict__ xbA, bf16* __restrict__ xbB) {
  const int n = blockIdx.x, k = threadIdx.x;  // 288 threads, y = side
  const float* x = blockIdx.y ? xB : xA;
  bf16* xb = blockIdx.y ? xbB : xbA;
  bf16 v = (bf16)0.f;
  if (k < DIN) v = (bf16)x[(long)n * DIN + k];
  else if (k == DIN) v = (bf16)1.f;  // bias-1 slot (WbT pads are 0 there)
  xb[(long)n * KP + k] = v;
}

__global__ void cvt_w_kernel(const float* __restrict__ Wq, const float* __restrict__ Wk,
                             const float* __restrict__ Wv, bf16* __restrict__ WbTq,
                             bf16* __restrict__ WbTk, bf16* __restrict__ WbTv) {
  const int which = blockIdx.y;
  const int h = blockIdx.x >> 8, n = blockIdx.x & 255, k = threadIdx.x;
  const float* W = which == 0 ? Wq : (which == 1 ? Wk : Wv);
  bf16* o = which == 0 ? WbTq : (which == 1 ? WbTk : WbTv);
  o[((long)h * 256 + n) * KP + k] =
      (k < DIN) ? (bf16)W[((long)h * DIN + k) * DS + n] : (bf16)0.f;
}

// WpT[(which*HH+h)][m][k] = sum_d W[h][k][d]*proj[d][m]; k=257 row = b.proj
__global__ void cvt_wp_kernel(const float* __restrict__ Wq, const float* __restrict__ Wk,
                              const float* __restrict__ bq, const float* __restrict__ bk,
                              const float* __restrict__ proj, bf16* __restrict__ WpT) {
  const int k = blockIdx.x, h = blockIdx.y, which = blockIdx.z, m = threadIdx.x;
  const float* W = which ? Wk : Wq;
  const float* bb = which ? bk : bq;
  float acc = 0.f;
  if (k < DIN) {
    const float* wr = W + ((long)h * DIN + k) * DS;
#pragma unroll 8
    for (int d = 0; d < DS; d++) acc = fmaf(wr[d], proj[(long)d * MF + m], acc);
  } else if (k == DIN) {
    const float* br = bb + (long)h * DS;
#pragma unroll 8
    for (int d = 0; d < DS; d++) acc = fmaf(br[d], proj[(long)d * MF + m], acc);
  }
  WpT[(((long)which * HH + h) * MF + m) * KP + k] = (bf16)acc;
}

// ---------------------------------------------------------------------------
// async global->LDS 16B helper
// ---------------------------------------------------------------------------
__device__ __forceinline__ void gl_lds16(const bf16* g, bf16* l) {
  __builtin_amdgcn_global_load_lds(
      (const __attribute__((address_space(1))) unsigned int*)g,
      (__attribute__((address_space(3))) unsigned int*)l, 16, 0, 0);
}

// ---------------------------------------------------------------------------
// proj4+feat fused: LDS-staged double-buffered projection GEMM. grid (24, 313).
// blockIdx.x = zh (z*4+h, FAST dim -> A-tile L2 reuse across the 8 XCDs).
// z: 0=value-u 1=value-i 2=q-u 3=k-u 4=q-i 5=k-i
// Block = 64 rows x 256 cols, 4 waves, acc 4x4; R7-verified 2-barrier sync.
// z>=2 blocks also compute the feat output (x @ WpT slice) and consume their
// own row-norms as fr from LDS (standalone feat kernel eliminated, R10).
// (R13: byte-identical to the R10-verified proj4.)
// ---------------------------------------------------------------------------
__global__ __launch_bounds__(256) void proj4_kernel(
    const bf16* __restrict__ xbA, const bf16* __restrict__ xbB,
    const bf16* __restrict__ WbTq, const bf16* __restrict__ WbTk,
    const bf16* __restrict__ WbTv, const bf16* __restrict__ WpT,
    const float* __restrict__ bq, const float* __restrict__ bk,
    const float* __restrict__ bv,
    bf16* __restrict__ voA, bf16* __restrict__ voB,
    bf16* __restrict__ qpA, bf16* __restrict__ kpA,
    bf16* __restrict__ qpB, bf16* __restrict__ kpB)
{
  __shared__ __align__(16) char smem[40960];
  bf16* Ab = (bf16*)smem;              // 2 * 2048 elems
  bf16* Bb = (bf16*)(smem + 8192);     // 2 * 8192 elems
  float (*rs)[4] = (float(*)[4])smem;
  float* frl = (float*)(smem + 2048);

  const int t = threadIdx.x;
  const int zh = blockIdx.x;
  const int h = zh & 3;
  const int z = zh >> 2;
  const int n0 = blockIdx.y * 64;
  const bf16* xb = (z == 1 || z >= 4) ? xbB : xbA;
  const bf16* WbT = (z < 2) ? WbTv : ((z == 2 || z == 4) ? WbTq : WbTk);
  const float* bsel = (z < 2) ? bv : ((z == 2 || z == 4) ? bq : bk);
  const int w = t >> 6, lane = t & 63;
  const int m16 = lane & 15, q = lane >> 4;
  const bf16* wbh = WbT + (long)h * 256 * KP;

  const int rsub = w * 16 + (lane >> 2);
  const int cb = (lane & 3) * 8;
  const bf16* gA = xb + (long)min(n0 + rsub, NR - 1) * KP + cb;
  const bf16* gB = wbh + (long)rsub * KP + cb;

  const int which = (z == 2 || z == 4) ? 0 : 1;
  const bf16* gWp = WpT + (((long)which * HH + h) * MF + (w * 16 + m16)) * KP + q * 8;

#define STAGE(buf, c)                                                        \
  do {                                                                       \
    const int _k0 = (c) * 32;                                                \
    gl_lds16(gA + _k0, Ab + (buf) * 2048 + w * 512);                         \
    _Pragma("unroll")                                                        \
    for (int e = 0; e < 4; e++)                                              \
      gl_lds16(gB + (long)e * 64 * KP + _k0,                                 \
               Bb + (buf) * 8192 + e * 2048 + w * 512);                      \
  } while (0)

  f32x4 acc[4][4] = {};
  f32x4 acc5[4] = {};
  STAGE(0, 0);

  for (int c = 0; c < 9; c++) {
    const int cur = c & 1;
    __syncthreads();  // drains vmcnt -> buf[cur] landed; all waves done with buf[1-cur]
    if (c < 8) STAGE(1 - cur, c + 1);

    bf16x8 af[4], bfj[4];
#pragma unroll
    for (int i = 0; i < 4; i++)
      af[i] = *(const bf16x8*)(Ab + cur * 2048 + (i * 16 + m16) * 32 + q * 8);
#pragma unroll
    for (int j = 0; j < 4; j++)
      bfj[j] = *(const bf16x8*)(Bb + cur * 8192 + (w * 64 + j * 16 + m16) * 32 + q * 8);
#pragma unroll
    for (int i = 0; i < 4; i++)
#pragma unroll
      for (int j = 0; j < 4; j++)
        acc[i][j] = __builtin_amdgcn_mfma_f32_16x16x32_bf16(af[i], bfj[j], acc[i][j], 0, 0, 0);
    if (z >= 2) {
      const bf16x8 bf5 = *(const bf16x8*)(gWp + c * 32);
#pragma unroll
      for (int i = 0; i < 4; i++)
        acc5[i] = __builtin_amdgcn_mfma_f32_16x16x32_bf16(af[i], bf5, acc5[i], 0, 0, 0);
    }
  }
#undef STAGE

  __syncthreads();  // all waves done reading Ab before rs/frl overlay it

  float bias[4];
#pragma unroll
  for (int j = 0; j < 4; j++) bias[j] = bsel[h * DS + w * 64 + j * 16 + m16];
#pragma unroll
  for (int i = 0; i < 4; i++)
#pragma unroll
    for (int r = 0; r < 4; r++) {
      float s = 0.f;
#pragma unroll
      for (int j = 0; j < 4; j++) {
        acc[i][j][r] += bias[j];
        s = fmaf(acc[i][j][r], acc[i][j][r], s);
      }
      for (int off = 1; off < 16; off <<= 1) s += __shfl_xor(s, off);
      if (m16 == 0) rs[i * 16 + q * 4 + r][w] = s;
    }
  __syncthreads();

  if (z < 2) {
    bf16* vout = z ? voB : voA;
    if (t < 64) {
      const float ss = rs[t][0] + rs[t][1] + rs[t][2] + rs[t][3];
      if (n0 + t < NR) vout[((long)h * NR + n0 + t) * VP] = (bf16)sqrtf(1.f + ss);
    }
#pragma unroll
    for (int i = 0; i < 4; i++) {
      const int row = i * 16 + q * 4;
#pragma unroll
      for (int r = 0; r < 4; r++) {
        const int rg = n0 + row + r;
        if (rg < NR) {
          bf16* vo = vout + ((long)h * NR + rg) * VP + 1 + w * 64 + m16;
          vo[0] = (bf16)acc[i][0][r]; vo[16] = (bf16)acc[i][1][r];
          vo[32] = (bf16)acc[i][2][r]; vo[48] = (bf16)acc[i][3][r];
        }
      }
    }
  } else {
    // fr into LDS (row-norm front factor), then feat output from acc5.
    if (t < 64) {
      const float ss = rs[t][0] + rs[t][1] + rs[t][2] + rs[t][3];
      frl[t] = 0.125f * __expf(-ss) + 1e-8f;
    }
    __syncthreads();
    bf16* fout = (z == 2) ? qpA : (z == 3) ? kpA : (z == 4) ? qpB : kpB;
    const float SQ2 = 1.41421356237309515f;
#pragma unroll
    for (int i = 0; i < 4; i++) {
      const int row = i * 16 + q * 4;
#pragma unroll
      for (int r = 0; r < 4; r++) {
        const int rg = n0 + row + r;
        if (rg < NR) {
          const float frv = frl[row + r];
          fout[((long)h * NR + rg) * MF + w * 16 + m16] =
              (bf16)(__expf(SQ2 * acc5[i][r]) * frv);
        }
      }
    }
  }
}

// ---------------------------------------------------------------------------
// last3: MFMA lastT[d][m] = sum_n v[n][d]*f[n][m]. grid (5, 25, 8).
// R13: LDS DOUBLE-BUFFER, ONE barrier per chunk (mirrors proj4's verified
// {load next | compute cur | barrier} template; __syncthreads only).
// R11's issue-early-across-barrier reverted (barrier drains vmcnt -> the
// prefetch was force-waited at the barrier; measured +13us regression).
// Per chunk: loads for c+1 issue at phase top, MFMA on buf[cur] runs under
// them, regs written to buf[1-cur], one barrier.
// ---------------------------------------------------------------------------
__global__ __launch_bounds__(256) void last3_kernel(
    const bf16* __restrict__ vA, const bf16* __restrict__ fA,
    const bf16* __restrict__ vB, const bf16* __restrict__ fB,
    float* __restrict__ part)
{
  __shared__ unsigned int Va[2][64 * 17];
  __shared__ unsigned int Fa[2][64 * 17];
  const int t = threadIdx.x;
  const int dt = blockIdx.x, kc = blockIdx.y, z = blockIdx.z;
  const int side = z >> 2, h = z & 3;
  const bf16* v = side ? vB : vA;
  const bf16* f = side ? fB : fA;
  const int d0 = dt * 64;
  const int w = t >> 6, lane = t & 63;
  const int m16 = lane & 15, q = lane >> 4;
  const int np = t >> 4, xg = (t & 15) * 4;
  f32x4 acc[4] = {};

  auto loadv = [&](int c, bf16x4& a0, bf16x4& a1) {
    const int n0c = (kc * LKC + c) * 32;
    const bf16* s0 = v + ((long)h * NR + n0c + 2 * np) * VP + d0 + xg;
    const bf16* s1 = s0 + VP;
    if (d0 + xg + 3 < DIN) {
      a0 = *(const bf16x4*)s0;
      a1 = *(const bf16x4*)s1;
    } else {
#pragma unroll
      for (int e = 0; e < 4; e++) {
        const bool ok = (d0 + xg + e < DIN);
        a0[e] = ok ? s0[e] : (bf16)0.f;
        a1[e] = ok ? s1[e] : (bf16)0.f;
      }
    }
  };
  auto loadf = [&](int c, bf16x4& g0, bf16x4& g1) {
    const int n0c = (kc * LKC + c) * 32;
    const bf16* s0 = f + ((long)h * NR + n0c + 2 * np) * MF + xg;
    g0 = *(const bf16x4*)s0;
    g1 = *(const bf16x4*)(s0 + MF);
  };
  auto lwrite = [&](int buf, const bf16x4& a0, const bf16x4& a1,
                    const bf16x4& g0, const bf16x4& g1) {
#pragma unroll
    for (int e = 0; e < 4; e++) {
      bf16x2 pv; pv[0] = a0[e]; pv[1] = a1[e];
      Va[buf][(xg + e) * 17 + np] = __builtin_bit_cast(unsigned int, pv);
      bf16x2 pf; pf[0] = g0[e]; pf[1] = g1[e];
      Fa[buf][(xg + e) * 17 + np] = __builtin_bit_cast(unsigned int, pf);
    }
  };

  bf16x4 va0, va1, vf0, vf1;
  loadv(0, va0, va1);
  loadf(0, vf0, vf1);
  lwrite(0, va0, va1, vf0, vf1);
  __syncthreads();

  for (int c = 0; c < LKC; c++) {
    const int cur = c & 1;
    // issue next chunk's loads (consumed after this phase's MFMAs)
    if (c + 1 < LKC) { loadv(c + 1, va0, va1); loadf(c + 1, vf0, vf1); }

    u32x4 bw;
#pragma unroll
    for (int c4 = 0; c4 < 4; c4++) bw[c4] = Fa[cur][(w * 16 + m16) * 17 + q * 4 + c4];
    const bf16x8 bvv = __builtin_bit_cast(bf16x8, bw);
#pragma unroll
    for (int i = 0; i < 4; i++) {
      u32x4 aw;
#pragma unroll
      for (int c4 = 0; c4 < 4; c4++) aw[c4] = Va[cur][(i * 16 + m16) * 17 + q * 4 + c4];
      acc[i] = __builtin_amdgcn_mfma_f32_16x16x32_bf16(
          __builtin_bit_cast(bf16x8, aw), bvv, acc[i], 0, 0, 0);
    }
    // write next chunk into the other buffer (prev phase's barrier protects it)
    if (c + 1 < LKC) lwrite(1 - cur, va0, va1, vf0, vf1);
    __syncthreads();
  }

  float* pp = part + ((long)(z * LKC + kc) * 5 + dt) * 4096;
#pragma unroll
  for (int i = 0; i < 4; i++)
#pragma unroll
    for (int r = 0; r < 4; r++)
      pp[(i * 16 + q * 4 + r) * 64 + w * 16 + m16] = acc[i][r];
}

__global__ void reduce_last4(const float* __restrict__ part,
                             bf16* __restrict__ hiU, bf16* __restrict__ loU,
                             bf16* __restrict__ hiI, bf16* __restrict__ loI) {
  const int d = blockIdx.x, zz = blockIdx.y, m = threadIdx.x;  // (272, 8) x 64
  const int side = zz >> 2, h = zz & 3;
  const int dt = d >> 6, dl = d & 63;
  float s = 0.f;
#pragma unroll 5
  for (int kc = 0; kc < LKC; kc++)
    s += part[((long)(zz * LKC + kc) * 5 + dt) * 4096 + dl * 64 + m];
  bf16* hi = side ? hiI : hiU;
  bf16* lo = side ? loI : loU;
  const bf16 hv = (bf16)s;
  hi[((long)h * LTP + d) * MF + m] = hv;
  lo[((long)h * LTP + d) * MF + m] = (bf16)(s - (float)hv);
}

// ---------------------------------------------------------------------------
// fuse3: v is BF16 (VP-stride rows); vreg converted bf16->f32 on load.
// (R13: reverted to the R10-verified form -- R11's jt fragment pipeline was
// part of a net-regressing change-set and is removed for clean attribution.)
// ---------------------------------------------------------------------------
__global__ __launch_bounds__(256) void fuse3_kernel(
    const bf16* __restrict__ qpA, const bf16* __restrict__ vA,
    const bf16* __restrict__ hiA, const bf16* __restrict__ loA,
    const bf16* __restrict__ qpB, const bf16* __restrict__ vB,
    const bf16* __restrict__ hiB, const bf16* __restrict__ loB,
    float* __restrict__ out)
{
  __shared__ __align__(16) float zs[32 * ZST];

  const int side = blockIdx.y;
  const bf16* qp = side ? qpB : qpA;
  const bf16* v = side ? vB : vA;
  const bf16* hi = side ? hiB : hiA;
  const bf16* lo = side ? loB : loA;
  float* o = out + (long)side * NR * DIN;

  const int t = threadIdx.x;
  const int n0 = blockIdx.x * 32;
  const int w = t >> 6, lane = t & 63;
  const int m16 = lane & 15, q = lane >> 4;
  const int erow = t >> 3, ecol = (t & 7) * 4;
  const bool lead = ((t & 7) == 0);
  const int ntile = (w == 0) ? 5 : 4;

  f32x4 macc[8] = {};
  float macc256 = 0.f;

  for (int h = 0; h < HH; h++) {
    const bf16* vr = v + ((long)h * NR + n0 + erow) * VP;
    f32x4 vreg[8];
#pragma unroll
    for (int it = 0; it < 8; it++) {
      const bf16x4 vb = *(const bf16x4*)(vr + it * 32 + ecol);
#pragma unroll
      for (int c = 0; c < 4; c++) vreg[it][c] = (float)vb[c];
    }
    float v256 = lead ? (float)vr[256] : 0.f;

    bf16x8 af[2][2];
#pragma unroll
    for (int i = 0; i < 2; i++)
#pragma unroll
      for (int hf = 0; hf < 2; hf++)
        af[i][hf] = *(const bf16x8*)(qp + ((long)h * NR + n0 + i * 16 + m16) * MF + hf * 32 + q * 8);

    for (int jt = 0; jt < ntile; jt++) {
      const int dt = (jt < 4) ? (w + jt * 4) : 16;
      const int d = dt * 16 + m16;
      const bf16* ph = hi + ((long)h * LTP + d) * MF + q * 8;
      const bf16* pl = lo + ((long)h * LTP + d) * MF + q * 8;
      const bf16x8 bh0 = *(const bf16x8*)ph, bh1 = *(const bf16x8*)(ph + 32);
      const bf16x8 bl0 = *(const bf16x8*)pl, bl1 = *(const bf16x8*)(pl + 32);
#pragma unroll
      for (int i = 0; i < 2; i++) {
        f32x4 a = {0.f, 0.f, 0.f, 0.f};
        a = __builtin_amdgcn_mfma_f32_16x16x32_bf16(af[i][1], bl1, a, 0, 0, 0);
        a = __builtin_amdgcn_mfma_f32_16x16x32_bf16(af[i][0], bl0, a, 0, 0, 0);
        a = __builtin_amdgcn_mfma_f32_16x16x32_bf16(af[i][1], bh1, a, 0, 0, 0);
        a = __builtin_amdgcn_mfma_f32_16x16x32_bf16(af[i][0], bh0, a, 0, 0, 0);
#pragma unroll
        for (int r = 0; r < 4; r++)
          zs[(i * 16 + q * 4 + r) * ZST + d] = a[r];
      }
    }
    __syncthreads();

    f32x4 zreg[8];
    float sz2 = 0.f, svz = 0.f, z0p = 0.f, v02p = 0.f;
#pragma unroll
    for (int it = 0; it < 8; it++) {
      zreg[it] = *(const f32x4*)&zs[erow * ZST + it * 32 + ecol];
#pragma unroll
      for (int c = 0; c < 4; c++) {
        sz2 = fmaf(zreg[it][c], zreg[it][c], sz2);
        svz = fmaf(vreg[it][c], zreg[it][c], svz);
      }
    }
    float z256 = 0.f;
    if (lead) {
      z256 = zs[erow * ZST + 256];
      sz2 = fmaf(z256, z256, sz2);
      svz = fmaf(v256, z256, svz);
      z0p = zreg[0][0];
      v02p = vreg[0][0] * vreg[0][0];
    }
#pragma unroll
    for (int off = 1; off < 8; off <<= 1) {
      sz2 += __shfl_xor(sz2, off);
      svz += __shfl_xor(svz, off);
      z0p += __shfl_xor(z0p, off);
      v02p += __shfl_xor(v02p, off);
    }
    const float a2 = 2.f * v02p - 1.f;
    const float mn = sz2 - 2.f * z0p * z0p;
    const float cf = 1.f / sqrtf(fabsf(mn + 1e-7f));
    const float ab = cf * svz;
    const float b2 = cf * cf * sz2;
    const float den = 1.f + 2.f * ab + a2 * b2;
    const float inv = 0.25f / (den + 1e-7f);
    const float sx = (1.f + 2.f * ab + b2) * inv;
    const float sy = (1.f - a2) * cf * inv;
#pragma unroll
    for (int it = 0; it < 8; it++)
#pragma unroll
      for (int c = 0; c < 4; c++)
        macc[it][c] = fmaf(sx, vreg[it][c], fmaf(sy, zreg[it][c], macc[it][c]));
    if (lead) macc256 = fmaf(sx, v256, fmaf(sy, z256, macc256));
    __syncthreads();
  }

  float sm2 = 0.f, m02p = 0.f;
#pragma unroll
  for (int it = 0; it < 8; it++)
#pragma unroll
    for (int c = 0; c < 4; c++) sm2 = fmaf(macc[it][c], macc[it][c], sm2);
  if (lead) {
    sm2 = fmaf(macc256, macc256, sm2);
    m02p = macc[0][0] * macc[0][0];
  }
#pragma unroll
  for (int off = 1; off < 8; off <<= 1) {
    sm2 += __shfl_xor(sm2, off);
    m02p += __shfl_xor(m02p, off);
  }
  const float fv = 1.f / sqrtf(fabsf(sm2 - 2.f * m02p) + 1e-7f);
  float* orow = o + (long)(n0 + erow) * DIN;
#pragma unroll
  for (int it = 0; it < 8; it++)
#pragma unroll
    for (int c = 0; c < 4; c++) orow[it * 32 + ecol + c] = macc[it][c] * fv;
  if (lead) orow[256] = macc256 * fv;
}

extern "C" void kernel_launch(void* const* d_in, const int* in_sizes, int n_in,
                              void* d_out, int out_size, void* d_ws, size_t ws_size,
                              hipStream_t stream) {
  const float* u    = (const float*)d_in[0];
  const float* ii   = (const float*)d_in[1];
  const float* Wk   = (const float*)d_in[2];
  const float* bk   = (const float*)d_in[3];
  const float* Wq   = (const float*)d_in[4];
  const float* bq   = (const float*)d_in[5];
  const float* Wv   = (const float*)d_in[6];
  const float* bv   = (const float*)d_in[7];
  const float* proj = (const float*)d_in[8];
  float* out = (float*)d_out;

  const long NVB = (long)HH * NR * VP;   // v in bf16, VP-padded rows
  const long NF = (long)HH * NR * MF;
  const long NLT = (long)HH * LTP * MF;
  bf16* v_u = (bf16*)d_ws;
  bf16* v_i = v_u + NVB;
  bf16* qp_u = v_i + NVB;
  bf16* kp_u = qp_u + NF;
  bf16* qp_i = kp_u + NF;
  bf16* kp_i = qp_i + NF;
  bf16* ltHi_u = kp_i + NF;
  bf16* ltLo_u = ltHi_u + NLT;
  bf16* ltHi_i = ltLo_u + NLT;
  bf16* ltLo_i = ltHi_i + NLT;
  bf16* xb_u  = ltLo_i + NLT;
  bf16* xb_i  = xb_u + (long)NR * KP;
  bf16* WbTq  = xb_i + (long)NR * KP;
  bf16* WbTk  = WbTq + 4 * 256 * KP;
  bf16* WbTv  = WbTk + 4 * 256 * KP;
  bf16* WpT   = WbTv + 4 * 256 * KP;   // 8 * 64 * KP bf16
  float* part = (float*)xb_u;  // 16.4 MB split-K partials, alias xb (dead after proj4)

  cvt_x_kernel<<<dim3(NR, 2), KP, 0, stream>>>(u, ii, xb_u, xb_i);
  cvt_w_kernel<<<dim3(1024, 3), KP, 0, stream>>>(Wq, Wk, Wv, WbTq, WbTk, WbTv);
  cvt_wp_kernel<<<dim3(KP, HH, 2), 64, 0, stream>>>(Wq, Wk, bq, bk, proj, WpT);

  // zh fast (24 A-sharing blocks consecutive -> XCD L2 reuse), 64-row tiles.
  // feat fused into z>=2 blocks (qp/kp written here; fr internal to LDS).
  proj4_kernel<<<dim3(24, (NR + 63) / 64), 256, 0, stream>>>(
      xb_u, xb_i, WbTq, WbTk, WbTv, WpT, bq, bk, bv,
      v_u, v_i, qp_u, kp_u, qp_i, kp_i);

  // side 0 (-> lastT_u) uses (v_i, kp_i); side 1 (-> lastT_i) uses (v_u, kp_u)
  last3_kernel<<<dim3(5, LKC, 8), 256, 0, stream>>>(v_i, kp_i, v_u, kp_u, part);
  reduce_last4<<<dim3(LTP, 8), 64, 0, stream>>>(part, ltHi_u, ltLo_u, ltHi_i, ltLo_i);

  fuse3_kernel<<<dim3(NR / 32, 2), 256, 0, stream>>>(
      qp_u, v_u, ltHi_u, ltLo_u, qp_i, v_i, ltHi_i, ltLo_i, out);
}